// Round 10
// baseline (35.328 us; speedup 1.0000x reference)
//
#include <hip/hip_runtime.h>

#define CC 16
#define OO 32
#define LL 65536   // 256*256

typedef __attribute__((ext_vector_type(8))) short bf16x8;
typedef __attribute__((ext_vector_type(4))) float f32x4;
typedef __attribute__((ext_vector_type(4))) int   i32x4;

static __device__ __forceinline__ ushort f2b(float f) {   // exact RNE (prepass)
    union { float f; unsigned u; } v; v.f = f;
    return (ushort)((v.u + 0x7fff + ((v.u >> 16) & 1)) >> 16);
}
// pack two floats -> (bf16(fh)<<16)|bf16(fl), round-half-up (3 ops) — proven R2-R9
static __device__ __forceinline__ unsigned pk2(float fl, float fh) {
    unsigned ul = __float_as_uint(fl) + 0x8000u;
    unsigned uh = __float_as_uint(fh) + 0x8000u;
    return __builtin_amdgcn_perm(uh, ul, 0x07060302);
}
// truncating pack (1 op) — phase-2 hid*pc products only (absmax-verified R9)
static __device__ __forceinline__ unsigned pkt(float fl, float fh) {
    return __builtin_amdgcn_perm(__float_as_uint(fh), __float_as_uint(fl), 0x07060302);
}

// ---- prepass: weights -> bf16 in exact MFMA A-fragment order (unchanged) ----
__global__ void prepass(const float* __restrict__ W1, const float* __restrict__ b1,
                        const float* __restrict__ W2, const float* __restrict__ b2,
                        const float* __restrict__ bias,
                        ushort* __restrict__ w1f, ushort* __restrict__ w2f) {
    int idx = blockIdx.x * 256 + threadIdx.x;
    if (idx < 5120) {
        int f = idx >> 9, lane = (idx >> 3) & 63, j = idx & 7;
        int ks = f >> 1, ot = f & 1, lm = lane & 15, g = lane >> 4;
        int o = ot * 16 + lm, kk = ks * 32 + g * 8 + j;
        int r = kk >> 4, c = kk & 15;
        float v = (kk < 144) ? W1[o * 144 + c * 9 + r] : (kk == 144 ? b1[o] : 0.f);
        w1f[idx] = f2b(v);
    } else if (idx < 15360) {
        int i2 = idx - 5120;
        int f = i2 >> 9, lane = (i2 >> 3) & 63, j = i2 & 7;
        int ks = f >> 1, ot = f & 1, lm = lane & 15, g = lane >> 4;
        int o = ot * 16 + lm, kk = ks * 32 + g * 8 + j;
        float v;
        if      (kk < 288) v = W2[o * 288 + kk];
        else if (kk < 297) v = b2[o * 9 + (kk - 288)];
        else if (kk == 297) v = bias[o];
        else               v = 0.f;
        w2f[i2] = f2b(v);
    }
}

// ---- main: 256 thr, 1 row/block, grid 1024 = 4 blocks/CU (4 waves/SIMD) ----
// W1 in regs; W2 fragments loaded per-tile from global (L1-resident, 20 KB).
__global__ __launch_bounds__(256, 4) void dynaconv_mfma(
    const float* __restrict__ x, const ushort* __restrict__ w1f,
    const ushort* __restrict__ w2f, float* __restrict__ out)
{
    __shared__ __align__(16) ushort xs[3][258][16];   // 24,768 B: rows h-1..h+1, halo cols 0/257=0
    __shared__ __align__(16) float  S[3][258];        //  3,096 B: channel sums
    __shared__ __align__(16) float  hidT[4][16][36];  //  9,216 B: per-wave hid transpose

    const int tid  = threadIdx.x;
    const int wv   = tid >> 6;
    const int lane = tid & 63;
    const int g    = lane >> 4;
    const int lm   = lane & 15;

    // XCD-chunked swizzle (1024 = 8*128, bijective)
    const int vbid = (blockIdx.x & 7) * 128 + (blockIdx.x >> 3);
    const int b    = vbid >> 8;
    const int h    = vbid & 255;

    // ---- W1 fragments -> regs (40 VGPR) ----
    bf16x8 W1R[10];
#pragma unroll
    for (int f = 0; f < 10; ++f) W1R[f] = *(const bf16x8*)(w1f + (f * 64 + lane) * 8);

    // ---- stage 3 rows x 256 cols x 16 ch -> bf16 LDS + fp32 channel sums ----
    const float* xb = x + b * (CC * LL);
    {
        int offr[3]; bool okr[3];
#pragma unroll
        for (int r = 0; r < 3; ++r) {
            const int hh = h - 1 + r;
            okr[r] = (unsigned)hh < 256u;
            offr[r] = (okr[r] ? hh : 0) * 256 + tid;
        }
        float sr[3] = {0.f, 0.f, 0.f};
#pragma unroll
        for (int cp = 0; cp < 8; ++cp) {
            const float* p0 = xb + (2 * cp) * LL;
            const float* p1 = p0 + LL;
#pragma unroll
            for (int r = 0; r < 3; ++r) {
                float va = p0[offr[r]], vb = p1[offr[r]];
                va = okr[r] ? va : 0.f; vb = okr[r] ? vb : 0.f;
                sr[r] += va + vb;
                *(unsigned*)&xs[r][tid + 1][2 * cp] = pk2(va, vb);
            }
        }
#pragma unroll
        for (int r = 0; r < 3; ++r) S[r][tid + 1] = sr[r];
        if (tid < 48) { int r = tid >> 4, side = (tid >> 3) & 1, cw = tid & 7;
                        *(unsigned*)&xs[r][side * 257][2 * cw] = 0u; }
        if (tid < 6)  S[tid >> 1][(tid & 1) * 257] = 0.f;
    }
    __syncthreads();   // the only barrier

    // per-ks feat LDS offsets (ushort units), loop-invariant
    int soff[5];
#pragma unroll
    for (int ks = 0; ks < 5; ++ks) {
        int r = 2 * ks + (g >> 1); if (r > 8) r = 8;
        int r3 = (r * 11) >> 5, rm = r - 3 * r3;
        soff[ks] = (r3 * 258 + rm + lm) * 16 + (g & 1) * 8;
    }
    const ushort* xsf = &xs[0][0][0];
    const ushort* w2g = w2f + lane * 8;   // per-lane base of W2 fragments (global, L1-hot)

#pragma unroll
    for (int t = 0; t < 4; ++t) {
        const int w0t = wv * 64 + t * 16;
        const int tb = w0t * 16;

        // ---- phase 1: hid[o,pixel] = W1e @ feat ----
        f32x4 a1[2] = {{0.f,0.f,0.f,0.f},{0.f,0.f,0.f,0.f}};
#pragma unroll
        for (int ks = 0; ks < 5; ++ks) {
            bf16x8 ff = *(const bf16x8*)(xsf + soff[ks] + tb);
            if (ks == 4) {               // g>=2: bias-extension K block
                i32x4 wd = *(i32x4*)&ff;
                wd[0] = (g < 2) ? wd[0] : (g == 2 ? 0x3F80 : 0);
                wd[1] = (g < 2) ? wd[1] : 0;
                wd[2] = (g < 2) ? wd[2] : 0;
                wd[3] = (g < 2) ? wd[3] : 0;
                ff = *(bf16x8*)&wd;
            }
            a1[0] = __builtin_amdgcn_mfma_f32_16x16x32_bf16(W1R[2 * ks],     ff, a1[0], 0, 0, 0);
            a1[1] = __builtin_amdgcn_mfma_f32_16x16x32_bf16(W1R[2 * ks + 1], ff, a1[1], 0, 0, 0);
        }

        // ---- tanh -> hidT (wave-private, no barrier) ----
#pragma unroll
        for (int ot = 0; ot < 2; ++ot)
#pragma unroll
            for (int q = 0; q < 4; ++q) {
                float e = __expf(2.f * a1[ot][q]);
                hidT[wv][lm][ot * 16 + g * 4 + q] = 1.f - 2.f / (e + 1.f);
            }
        f32x4 h0v = *(const f32x4*)&hidT[wv][lm][g * 8];
        f32x4 h1v = *(const f32x4*)&hidT[wv][lm][g * 8 + 4];

        float pcv[9];
#pragma unroll
        for (int r = 0; r < 9; ++r) pcv[r] = S[r / 3][w0t + lm + (r % 3)];

        // ---- phase 2: out[o,pixel] = W2p @ (pc ⊗ hid); W2 frags via global/L1 ----
        f32x4 a2[2] = {{0.f,0.f,0.f,0.f},{0.f,0.f,0.f,0.f}};
#pragma unroll
        for (int ks = 0; ks < 9; ++ks) {
            bf16x8 bm0 = *(const bf16x8*)(w2g + (2 * ks) * 512);
            bf16x8 bm1 = *(const bf16x8*)(w2g + (2 * ks + 1) * 512);
            const float p = pcv[ks];
            i32x4 wd;
            wd[0] = (int)pkt(h0v[0] * p, h0v[1] * p);
            wd[1] = (int)pkt(h0v[2] * p, h0v[3] * p);
            wd[2] = (int)pkt(h1v[0] * p, h1v[1] * p);
            wd[3] = (int)pkt(h1v[2] * p, h1v[3] * p);
            bf16x8 ff2 = *(bf16x8*)&wd;
            a2[0] = __builtin_amdgcn_mfma_f32_16x16x32_bf16(bm0, ff2, a2[0], 0, 0, 0);
            a2[1] = __builtin_amdgcn_mfma_f32_16x16x32_bf16(bm1, ff2, a2[1], 0, 0, 0);
        }
        {   // ks==9: K-extension block (b2·pc + bias) — RNE pack
            bf16x8 bm0 = *(const bf16x8*)(w2g + 18 * 512);
            bf16x8 bm1 = *(const bf16x8*)(w2g + 19 * 512);
            i32x4 wd;
            wd[0] = (g == 0) ? (int)pk2(pcv[0], pcv[1]) : ((g == 1) ? (int)pk2(pcv[8], 1.f) : 0);
            wd[1] = (g == 0) ? (int)pk2(pcv[2], pcv[3]) : 0;
            wd[2] = (g == 0) ? (int)pk2(pcv[4], pcv[5]) : 0;
            wd[3] = (g == 0) ? (int)pk2(pcv[6], pcv[7]) : 0;
            bf16x8 ff2 = *(bf16x8*)&wd;
            a2[0] = __builtin_amdgcn_mfma_f32_16x16x32_bf16(bm0, ff2, a2[0], 0, 0, 0);
            a2[1] = __builtin_amdgcn_mfma_f32_16x16x32_bf16(bm1, ff2, a2[1], 0, 0, 0);
        }

        // ---- stores straight from accumulator ----
        float* ob = out + b * (OO * LL) + h * 256 + w0t + lm;
#pragma unroll
        for (int ot = 0; ot < 2; ++ot)
#pragma unroll
            for (int q = 0; q < 4; ++q)
                ob[(ot * 16 + g * 4 + q) * LL] = a2[ot][q];
    }
}

extern "C" void kernel_launch(void* const* d_in, const int* in_sizes, int n_in,
                              void* d_out, int out_size, void* d_ws, size_t ws_size,
                              hipStream_t stream) {
    const float* x    = (const float*)d_in[0];
    const float* W1   = (const float*)d_in[1];
    const float* b1   = (const float*)d_in[2];
    const float* W2   = (const float*)d_in[3];
    const float* b2   = (const float*)d_in[4];
    const float* bias = (const float*)d_in[5];
    float* out = (float*)d_out;

    ushort* w1f = (ushort*)d_ws;        // 5120 bf16
    ushort* w2f = w1f + 5120;           // 10240 bf16

    prepass<<<60, 256, 0, stream>>>(W1, b1, W2, b2, bias, w1f, w2f);
    dynaconv_mfma<<<1024, 256, 0, stream>>>(x, w1f, w2f, out);
}

// Round 11
// 29.715 us; speedup vs baseline: 1.1889x; 1.1889x over previous
//
#include <hip/hip_runtime.h>

#define CC 16
#define OO 32
#define LL 65536   // 256*256

typedef __attribute__((ext_vector_type(8))) short bf16x8;
typedef __attribute__((ext_vector_type(4))) float f32x4;
typedef __attribute__((ext_vector_type(4))) int   i32x4;

static __device__ __forceinline__ ushort f2b(float f) {   // exact RNE (prepass)
    union { float f; unsigned u; } v; v.f = f;
    return (ushort)((v.u + 0x7fff + ((v.u >> 16) & 1)) >> 16);
}
// pack two floats -> (bf16(fh)<<16)|bf16(fl), round-half-up (3 ops) — proven R2-R10
static __device__ __forceinline__ unsigned pk2(float fl, float fh) {
    unsigned ul = __float_as_uint(fl) + 0x8000u;
    unsigned uh = __float_as_uint(fh) + 0x8000u;
    return __builtin_amdgcn_perm(uh, ul, 0x07060302);
}
// truncating pack (1 op) — phase-2 hid*pc products only (absmax-verified R9)
static __device__ __forceinline__ unsigned pkt(float fl, float fh) {
    return __builtin_amdgcn_perm(__float_as_uint(fh), __float_as_uint(fl), 0x07060302);
}

// ---- prepass: weights -> bf16 in exact MFMA A-fragment order (unchanged) ----
__global__ void prepass(const float* __restrict__ W1, const float* __restrict__ b1,
                        const float* __restrict__ W2, const float* __restrict__ b2,
                        const float* __restrict__ bias,
                        ushort* __restrict__ w1f, ushort* __restrict__ w2f) {
    int idx = blockIdx.x * 256 + threadIdx.x;
    if (idx < 5120) {
        int f = idx >> 9, lane = (idx >> 3) & 63, j = idx & 7;
        int ks = f >> 1, ot = f & 1, lm = lane & 15, g = lane >> 4;
        int o = ot * 16 + lm, kk = ks * 32 + g * 8 + j;
        int r = kk >> 4, c = kk & 15;
        float v = (kk < 144) ? W1[o * 144 + c * 9 + r] : (kk == 144 ? b1[o] : 0.f);
        w1f[idx] = f2b(v);
    } else if (idx < 15360) {
        int i2 = idx - 5120;
        int f = i2 >> 9, lane = (i2 >> 3) & 63, j = i2 & 7;
        int ks = f >> 1, ot = f & 1, lm = lane & 15, g = lane >> 4;
        int o = ot * 16 + lm, kk = ks * 32 + g * 8 + j;
        float v;
        if      (kk < 288) v = W2[o * 288 + kk];
        else if (kk < 297) v = b2[o * 9 + (kk - 288)];
        else if (kk == 297) v = bias[o];
        else               v = 0.f;
        w2f[i2] = f2b(v);
    }
}

// ---- main: 256 thr, 1 row/block, grid 1024; LDS 37.4KB (4 blocks/CU), regs <=128 ----
// W1 in regs; W2 fragments re-loaded per tile from global (L1-hot 20KB) — opaque
// pointer defeats CSE/LICM so they never occupy 80 resident regs.
__global__ __launch_bounds__(256, 2) void dynaconv_mfma(
    const float* __restrict__ x, const ushort* __restrict__ w1f,
    const ushort* __restrict__ w2f, float* __restrict__ out)
{
    __shared__ __align__(16) ushort xs[3][258][16];   // 24,768 B: rows h-1..h+1, halo cols 0/257=0
    __shared__ __align__(16) float  S[3][258];        //  3,096 B: channel sums
    __shared__ __align__(16) float  hidT[4][16][36];  //  9,216 B: per-wave hid transpose

    const int tid  = threadIdx.x;
    const int wv   = tid >> 6;
    const int lane = tid & 63;
    const int g    = lane >> 4;
    const int lm   = lane & 15;

    // XCD-chunked swizzle (1024 = 8*128, bijective)
    const int vbid = (blockIdx.x & 7) * 128 + (blockIdx.x >> 3);
    const int b    = vbid >> 8;
    const int h    = vbid & 255;

    // ---- W1 fragments -> regs (40 regs) ----
    bf16x8 W1R[10];
#pragma unroll
    for (int f = 0; f < 10; ++f) W1R[f] = *(const bf16x8*)(w1f + (f * 64 + lane) * 8);

    // ---- stage 3 rows x 256 cols x 16 ch -> bf16 LDS + fp32 channel sums ----
    const float* xb = x + b * (CC * LL);
    {
        int offr[3]; bool okr[3];
#pragma unroll
        for (int r = 0; r < 3; ++r) {
            const int hh = h - 1 + r;
            okr[r] = (unsigned)hh < 256u;
            offr[r] = (okr[r] ? hh : 0) * 256 + tid;
        }
        float sr[3] = {0.f, 0.f, 0.f};
#pragma unroll
        for (int cp = 0; cp < 8; ++cp) {
            const float* p0 = xb + (2 * cp) * LL;
            const float* p1 = p0 + LL;
#pragma unroll
            for (int r = 0; r < 3; ++r) {
                float va = p0[offr[r]], vb = p1[offr[r]];
                va = okr[r] ? va : 0.f; vb = okr[r] ? vb : 0.f;
                sr[r] += va + vb;
                *(unsigned*)&xs[r][tid + 1][2 * cp] = pk2(va, vb);
            }
        }
#pragma unroll
        for (int r = 0; r < 3; ++r) S[r][tid + 1] = sr[r];
        if (tid < 48) { int r = tid >> 4, side = (tid >> 3) & 1, cw = tid & 7;
                        *(unsigned*)&xs[r][side * 257][2 * cw] = 0u; }
        if (tid < 6)  S[tid >> 1][(tid & 1) * 257] = 0.f;
    }
    __syncthreads();   // the only barrier

    // per-ks feat LDS offsets (ushort units), loop-invariant
    int soff[5];
#pragma unroll
    for (int ks = 0; ks < 5; ++ks) {
        int r = 2 * ks + (g >> 1); if (r > 8) r = 8;
        int r3 = (r * 11) >> 5, rm = r - 3 * r3;
        soff[ks] = (r3 * 258 + rm + lm) * 16 + (g & 1) * 8;
    }
    const ushort* xsf = &xs[0][0][0];

#pragma unroll
    for (int t = 0; t < 4; ++t) {
        const int w0t = wv * 64 + t * 16;
        const int tb = w0t * 16;

        // opaque per-tile W2 base: compiler cannot CSE/hoist the 22 fragment loads
        const ushort* w2t = w2f + lane * 8;
        asm volatile("" : "+v"(w2t));

        // ---- phase 1: hid[o,pixel] = W1e @ feat ----
        f32x4 a1[2] = {{0.f,0.f,0.f,0.f},{0.f,0.f,0.f,0.f}};
#pragma unroll
        for (int ks = 0; ks < 5; ++ks) {
            bf16x8 ff = *(const bf16x8*)(xsf + soff[ks] + tb);
            if (ks == 4) {               // g>=2: bias-extension K block
                i32x4 wd = *(i32x4*)&ff;
                wd[0] = (g < 2) ? wd[0] : (g == 2 ? 0x3F80 : 0);
                wd[1] = (g < 2) ? wd[1] : 0;
                wd[2] = (g < 2) ? wd[2] : 0;
                wd[3] = (g < 2) ? wd[3] : 0;
                ff = *(bf16x8*)&wd;
            }
            a1[0] = __builtin_amdgcn_mfma_f32_16x16x32_bf16(W1R[2 * ks],     ff, a1[0], 0, 0, 0);
            a1[1] = __builtin_amdgcn_mfma_f32_16x16x32_bf16(W1R[2 * ks + 1], ff, a1[1], 0, 0, 0);
        }

        // ---- tanh -> hidT (wave-private, no barrier) ----
#pragma unroll
        for (int ot = 0; ot < 2; ++ot)
#pragma unroll
            for (int q = 0; q < 4; ++q) {
                float e = __expf(2.f * a1[ot][q]);
                hidT[wv][lm][ot * 16 + g * 4 + q] = 1.f - 2.f / (e + 1.f);
            }
        f32x4 h0v = *(const f32x4*)&hidT[wv][lm][g * 8];
        f32x4 h1v = *(const f32x4*)&hidT[wv][lm][g * 8 + 4];

        float pcv[9];
#pragma unroll
        for (int r = 0; r < 9; ++r) pcv[r] = S[r / 3][w0t + lm + (r % 3)];

        // ---- phase 2: out[o,pixel] = W2p @ (pc ⊗ hid); W2 frags via global/L1 ----
        f32x4 a2[2] = {{0.f,0.f,0.f,0.f},{0.f,0.f,0.f,0.f}};
#pragma unroll
        for (int ks = 0; ks < 9; ++ks) {
            bf16x8 bm0 = *(const bf16x8*)(w2t + (2 * ks) * 512);
            bf16x8 bm1 = *(const bf16x8*)(w2t + (2 * ks + 1) * 512);
            const float p = pcv[ks];
            i32x4 wd;
            wd[0] = (int)pkt(h0v[0] * p, h0v[1] * p);
            wd[1] = (int)pkt(h0v[2] * p, h0v[3] * p);
            wd[2] = (int)pkt(h1v[0] * p, h1v[1] * p);
            wd[3] = (int)pkt(h1v[2] * p, h1v[3] * p);
            bf16x8 ff2 = *(bf16x8*)&wd;
            a2[0] = __builtin_amdgcn_mfma_f32_16x16x32_bf16(bm0, ff2, a2[0], 0, 0, 0);
            a2[1] = __builtin_amdgcn_mfma_f32_16x16x32_bf16(bm1, ff2, a2[1], 0, 0, 0);
        }
        {   // ks==9: K-extension block (b2·pc + bias) — RNE pack
            bf16x8 bm0 = *(const bf16x8*)(w2t + 18 * 512);
            bf16x8 bm1 = *(const bf16x8*)(w2t + 19 * 512);
            i32x4 wd;
            wd[0] = (g == 0) ? (int)pk2(pcv[0], pcv[1]) : ((g == 1) ? (int)pk2(pcv[8], 1.f) : 0);
            wd[1] = (g == 0) ? (int)pk2(pcv[2], pcv[3]) : 0;
            wd[2] = (g == 0) ? (int)pk2(pcv[4], pcv[5]) : 0;
            wd[3] = (g == 0) ? (int)pk2(pcv[6], pcv[7]) : 0;
            bf16x8 ff2 = *(bf16x8*)&wd;
            a2[0] = __builtin_amdgcn_mfma_f32_16x16x32_bf16(bm0, ff2, a2[0], 0, 0, 0);
            a2[1] = __builtin_amdgcn_mfma_f32_16x16x32_bf16(bm1, ff2, a2[1], 0, 0, 0);
        }

        // ---- stores straight from accumulator ----
        float* ob = out + b * (OO * LL) + h * 256 + w0t + lm;
#pragma unroll
        for (int ot = 0; ot < 2; ++ot)
#pragma unroll
            for (int q = 0; q < 4; ++q)
                ob[(ot * 16 + g * 4 + q) * LL] = a2[ot][q];
    }
}

extern "C" void kernel_launch(void* const* d_in, const int* in_sizes, int n_in,
                              void* d_out, int out_size, void* d_ws, size_t ws_size,
                              hipStream_t stream) {
    const float* x    = (const float*)d_in[0];
    const float* W1   = (const float*)d_in[1];
    const float* b1   = (const float*)d_in[2];
    const float* W2   = (const float*)d_in[3];
    const float* b2   = (const float*)d_in[4];
    const float* bias = (const float*)d_in[5];
    float* out = (float*)d_out;

    ushort* w1f = (ushort*)d_ws;        // 5120 bf16
    ushort* w2f = w1f + 5120;           // 10240 bf16

    prepass<<<60, 256, 0, stream>>>(W1, b1, W2, b2, bias, w1f, w2f);
    dynaconv_mfma<<<1024, 256, 0, stream>>>(x, w1f, w2f, out);
}

// Round 12
// 28.066 us; speedup vs baseline: 1.2587x; 1.0588x over previous
//
#include <hip/hip_runtime.h>

#define CC 16
#define OO 32
#define LL 65536   // 256*256

typedef __attribute__((ext_vector_type(8))) short bf16x8;
typedef __attribute__((ext_vector_type(4))) float f32x4;
typedef __attribute__((ext_vector_type(4))) int   i32x4;

static __device__ __forceinline__ ushort f2b(float f) {   // exact RNE (prepass)
    union { float f; unsigned u; } v; v.f = f;
    return (ushort)((v.u + 0x7fff + ((v.u >> 16) & 1)) >> 16);
}
// pack two floats -> (bf16(fh)<<16)|bf16(fl), round-half-up (3 ops) — proven R2-R11
static __device__ __forceinline__ unsigned pk2(float fl, float fh) {
    unsigned ul = __float_as_uint(fl) + 0x8000u;
    unsigned uh = __float_as_uint(fh) + 0x8000u;
    return __builtin_amdgcn_perm(uh, ul, 0x07060302);
}
// truncating pack (1 op) — phase-2 hid*pc products only (absmax-verified R9)
static __device__ __forceinline__ unsigned pkt(float fl, float fh) {
    return __builtin_amdgcn_perm(__float_as_uint(fh), __float_as_uint(fl), 0x07060302);
}

// ---- prepass: weights -> bf16 in exact MFMA A-fragment order (unchanged) ----
__global__ void prepass(const float* __restrict__ W1, const float* __restrict__ b1,
                        const float* __restrict__ W2, const float* __restrict__ b2,
                        const float* __restrict__ bias,
                        ushort* __restrict__ w1f, ushort* __restrict__ w2f) {
    int idx = blockIdx.x * 256 + threadIdx.x;
    if (idx < 5120) {
        int f = idx >> 9, lane = (idx >> 3) & 63, j = idx & 7;
        int ks = f >> 1, ot = f & 1, lm = lane & 15, g = lane >> 4;
        int o = ot * 16 + lm, kk = ks * 32 + g * 8 + j;
        int r = kk >> 4, c = kk & 15;
        float v = (kk < 144) ? W1[o * 144 + c * 9 + r] : (kk == 144 ? b1[o] : 0.f);
        w1f[idx] = f2b(v);
    } else if (idx < 15360) {
        int i2 = idx - 5120;
        int f = i2 >> 9, lane = (i2 >> 3) & 63, j = i2 & 7;
        int ks = f >> 1, ot = f & 1, lm = lane & 15, g = lane >> 4;
        int o = ot * 16 + lm, kk = ks * 32 + g * 8 + j;
        float v;
        if      (kk < 288) v = W2[o * 288 + kk];
        else if (kk < 297) v = b2[o * 9 + (kk - 288)];
        else if (kk == 297) v = bias[o];
        else               v = 0.f;
        w2f[i2] = f2b(v);
    }
}

// ---- main: R9 champion structure, but tile loops ROLLED (I$-resident hot loop) ----
__global__ __launch_bounds__(256, 2) void dynaconv_mfma(
    const float* __restrict__ x, const ushort* __restrict__ w1f,
    const ushort* __restrict__ w2f, float* __restrict__ out)
{
    __shared__ __align__(16) ushort xs[4][260][24];  // bf16 x, rows h0-1..h0+2, halo cols 0/257=0
    __shared__ __align__(16) float  S[4][260];       // fp32 channel sums
    __shared__ __align__(16) float  hidT[4][16][36]; // per-wave hid transpose (wave-private)

    const int tid  = threadIdx.x;
    const int wv   = tid >> 6;
    const int lane = tid & 63;
    const int g    = lane >> 4;
    const int lm   = lane & 15;

    // XCD-chunked swizzle: blocks on one XCD process consecutive row-pairs (L2 reuse)
    const int vbid = (blockIdx.x & 7) * 64 + (blockIdx.x >> 3);   // 512 = 8*64, bijective
    const int b    = vbid >> 7;
    const int h0   = (vbid & 127) * 2;

    // ---- weight fragments -> regs (once per block) ----
    bf16x8 W1R[10], W2R[20];
#pragma unroll
    for (int f = 0; f < 10; ++f) W1R[f] = *(const bf16x8*)(w1f + (f * 64 + lane) * 8);
#pragma unroll
    for (int f = 0; f < 20; ++f) W2R[f] = *(const bf16x8*)(w2f + (f * 64 + lane) * 8);

    // ---- stage 4 rows x 256 cols x 16 ch -> bf16 LDS + fp32 channel sums ----
    const float* xb = x + b * (CC * LL);
    {
        int offr[4]; bool okr[4];
#pragma unroll
        for (int r = 0; r < 4; ++r) {
            const int hh = h0 - 1 + r;
            okr[r] = (unsigned)hh < 256u;
            offr[r] = (okr[r] ? hh : 0) * 256 + tid;
        }
        float sr[4] = {0.f, 0.f, 0.f, 0.f};
#pragma unroll
        for (int cp = 0; cp < 8; ++cp) {
            const float* p0 = xb + (2 * cp) * LL;
            const float* p1 = p0 + LL;
#pragma unroll
            for (int r = 0; r < 4; ++r) {
                float va = p0[offr[r]], vb = p1[offr[r]];
                va = okr[r] ? va : 0.f; vb = okr[r] ? vb : 0.f;
                sr[r] += va + vb;
                *(unsigned*)&xs[r][tid + 1][2 * cp] = pk2(va, vb);
            }
        }
#pragma unroll
        for (int r = 0; r < 4; ++r) S[r][tid + 1] = sr[r];
        if (tid < 128) { int r = tid >> 5, side = (tid >> 4) & 1, c = tid & 15; xs[r][side * 257][c] = 0; }
        if (tid < 8)   S[tid >> 1][(tid & 1) * 257] = 0.f;
    }
    __syncthreads();   // the only barrier

    // per-ks feat LDS offsets (ushort units), loop-invariant
    int soff[5];
#pragma unroll
    for (int ks = 0; ks < 5; ++ks) {
        int r = 2 * ks + (g >> 1); if (r > 8) r = 8;
        int r3 = (r * 11) >> 5, rm = r - 3 * r3;
        soff[ks] = (r3 * 260 + rm + lm) * 24 + (g & 1) * 8;
    }
    const ushort* xsf = &xs[0][0][0];

#pragma unroll 1
    for (int hr = 0; hr < 2; ++hr) {
        const int hb = hr * (260 * 24);
#pragma unroll 1
        for (int t = 0; t < 4; ++t) {
            const int w0t = wv * 64 + t * 16;
            const int tb = w0t * 24 + hb;

            // ---- phase 1: hid[o,pixel] = W1e @ feat ----
            f32x4 a1[2] = {{0.f,0.f,0.f,0.f},{0.f,0.f,0.f,0.f}};
#pragma unroll
            for (int ks = 0; ks < 5; ++ks) {
                bf16x8 ff = *(const bf16x8*)(xsf + soff[ks] + tb);
                if (ks == 4) {               // g>=2: bias-extension K block
                    i32x4 wd = *(i32x4*)&ff;
                    wd[0] = (g < 2) ? wd[0] : (g == 2 ? 0x3F80 : 0);
                    wd[1] = (g < 2) ? wd[1] : 0;
                    wd[2] = (g < 2) ? wd[2] : 0;
                    wd[3] = (g < 2) ? wd[3] : 0;
                    ff = *(bf16x8*)&wd;
                }
                a1[0] = __builtin_amdgcn_mfma_f32_16x16x32_bf16(W1R[2 * ks],     ff, a1[0], 0, 0, 0);
                a1[1] = __builtin_amdgcn_mfma_f32_16x16x32_bf16(W1R[2 * ks + 1], ff, a1[1], 0, 0, 0);
            }

            // ---- tanh -> hidT (wave-private) ----
#pragma unroll
            for (int ot = 0; ot < 2; ++ot)
#pragma unroll
                for (int q = 0; q < 4; ++q) {
                    float e = __expf(2.f * a1[ot][q]);
                    hidT[wv][lm][ot * 16 + g * 4 + q] = 1.f - 2.f / (e + 1.f);
                }
            f32x4 h0v = *(const f32x4*)&hidT[wv][lm][g * 8];
            f32x4 h1v = *(const f32x4*)&hidT[wv][lm][g * 8 + 4];

            float pcv[9];
#pragma unroll
            for (int r = 0; r < 9; ++r) pcv[r] = S[r / 3 + hr][w0t + lm + (r % 3)];

            // ---- phase 2: out[o,pixel] = W2p @ (pc ⊗ hid) — trunc pack ----
            f32x4 a2[2] = {{0.f,0.f,0.f,0.f},{0.f,0.f,0.f,0.f}};
#pragma unroll
            for (int ks = 0; ks < 9; ++ks) {
                const float p = pcv[ks];
                i32x4 wd;
                wd[0] = (int)pkt(h0v[0] * p, h0v[1] * p);
                wd[1] = (int)pkt(h0v[2] * p, h0v[3] * p);
                wd[2] = (int)pkt(h1v[0] * p, h1v[1] * p);
                wd[3] = (int)pkt(h1v[2] * p, h1v[3] * p);
                bf16x8 ff2 = *(bf16x8*)&wd;
                a2[0] = __builtin_amdgcn_mfma_f32_16x16x32_bf16(W2R[2 * ks],     ff2, a2[0], 0, 0, 0);
                a2[1] = __builtin_amdgcn_mfma_f32_16x16x32_bf16(W2R[2 * ks + 1], ff2, a2[1], 0, 0, 0);
            }
            {   // ks==9: K-extension block (b2·pc + bias) — RNE pack
                i32x4 wd;
                wd[0] = (g == 0) ? (int)pk2(pcv[0], pcv[1]) : ((g == 1) ? (int)pk2(pcv[8], 1.f) : 0);
                wd[1] = (g == 0) ? (int)pk2(pcv[2], pcv[3]) : 0;
                wd[2] = (g == 0) ? (int)pk2(pcv[4], pcv[5]) : 0;
                wd[3] = (g == 0) ? (int)pk2(pcv[6], pcv[7]) : 0;
                bf16x8 ff2 = *(bf16x8*)&wd;
                a2[0] = __builtin_amdgcn_mfma_f32_16x16x32_bf16(W2R[18], ff2, a2[0], 0, 0, 0);
                a2[1] = __builtin_amdgcn_mfma_f32_16x16x32_bf16(W2R[19], ff2, a2[1], 0, 0, 0);
            }

            // ---- stores straight from accumulator ----
            float* ob = out + b * (OO * LL) + (h0 + hr) * 256 + w0t + lm;
#pragma unroll
            for (int ot = 0; ot < 2; ++ot)
#pragma unroll
                for (int q = 0; q < 4; ++q)
                    ob[(ot * 16 + g * 4 + q) * LL] = a2[ot][q];
        }
    }
}

extern "C" void kernel_launch(void* const* d_in, const int* in_sizes, int n_in,
                              void* d_out, int out_size, void* d_ws, size_t ws_size,
                              hipStream_t stream) {
    const float* x    = (const float*)d_in[0];
    const float* W1   = (const float*)d_in[1];
    const float* b1   = (const float*)d_in[2];
    const float* W2   = (const float*)d_in[3];
    const float* b2   = (const float*)d_in[4];
    const float* bias = (const float*)d_in[5];
    float* out = (float*)d_out;

    ushort* w1f = (ushort*)d_ws;        // 5120 bf16
    ushort* w2f = w1f + 5120;           // 10240 bf16

    prepass<<<60, 256, 0, stream>>>(W1, b1, W2, b2, bias, w1f, w2f);
    dynaconv_mfma<<<512, 256, 0, stream>>>(x, w1f, w2f, out);
}